// Round 1
// baseline (1074.426 us; speedup 1.0000x reference)
//
#include <hip/hip_runtime.h>
#include <math.h>

#define BB_   16
#define NN_   2048
#define CDIM  10
#define KNN   16
#define NNODES (BB_*NN_)      // 32768
#define NEDGES (NNODES*KNN)   // 524288

// ---------------- prep: squared norms + zero indeg + SoA transpose ----------------
// xt[b][c][j] = x[b][j][c]  (c-plane writes are lane-coalesced)
__global__ __launch_bounds__(256) void prep_kernel(const float* __restrict__ x,
                                                   float* __restrict__ x2,
                                                   float* __restrict__ xt,
                                                   int* __restrict__ indeg) {
    int g = blockIdx.x * 256 + threadIdx.x;
    if (g >= NNODES) return;
    const int bb = g >> 11;
    const int j  = g & (NN_ - 1);
    const float* xr = x + (size_t)g * CDIM;
    float* xtb = xt + (size_t)bb * CDIM * NN_;
    float s = 0.f;
#pragma unroll
    for (int c = 0; c < CDIM; ++c) {
        float v = xr[c];
        s = fmaf(v, v, s);
        xtb[c * NN_ + j] = v;
    }
    x2[g] = s;
    indeg[g] = 0;
}

// order-preserving float->uint transform (handles negatives exactly)
__device__ __forceinline__ unsigned fkey(float f) {
    unsigned u = __float_as_uint(f);
    return ((int)u >= 0) ? (u ^ 0x80000000u) : ~u;
}

// full bitonic sort of (hi,lo) u64 keys across 64 lanes, ascending.
// keys MUST be unique (ties break permutation property).
__device__ __forceinline__ void bitonic64(unsigned& hi, unsigned& lo, int lane) {
#pragma unroll
    for (int k = 2; k <= 64; k <<= 1) {
#pragma unroll
        for (int j = k >> 1; j > 0; j >>= 1) {
            unsigned ohi = __shfl_xor(hi, j, 64);
            unsigned olo = __shfl_xor(lo, j, 64);
            bool up    = ((lane & k) == 0);
            bool lower = ((lane & j) == 0);
            bool oless = (ohi < hi) || (ohi == hi && olo < lo);  // other < mine
            bool take  = (lower == up) ? oless : !oless;
            hi = take ? ohi : hi;
            lo = take ? olo : lo;
        }
    }
}

// ---------------- kNN: one wave per row, threshold-select ----------------
// SoA candidate loads: 10 coalesced dword loads per 64-candidate batch
// (~40 L1 line-requests/iter vs ~200 for the 40B-stride AoS version).
// 8 rows per block (one batch) so L1 reuse covers the 88 KB batch planes.
__global__ __launch_bounds__(512) void knn_kernel(const float* __restrict__ x,
                                                  const float* __restrict__ xt,
                                                  const float* __restrict__ x2,
                                                  int* __restrict__ nbors,
                                                  int* __restrict__ indeg) {
    __shared__ unsigned s_hi[8][64];
    __shared__ unsigned s_lo[8][64];
    const int wv   = threadIdx.x >> 6;
    const int lane = threadIdx.x & 63;
    const int g  = blockIdx.x * 8 + wv;   // global row (node)
    const int bb = g >> 11;               // batch
    const int il = g & (NN_ - 1);         // local row index

    // own row (AoS, tiny)
    float xp[CDIM];
    const float* xr = x + (size_t)g * CDIM;
#pragma unroll
    for (int c = 0; c < CDIM; ++c) xp[c] = xr[c];
    const float  x2g = x2[g];
    const float* xtb = xt + (size_t)bb * CDIM * NN_;
    const float* x2b = x2 + bb * NN_;

    unsigned ud[32];
    unsigned min_hi = 0xFFFFFFFFu, min_lo = 0xFFFFFFFFu;
#pragma unroll
    for (int s = 0; s < 32; ++s) {
        const int jj = s * 64 + lane;
        float dot = 0.f;
#pragma unroll
        for (int c = 0; c < CDIM; ++c) dot = fmaf(xp[c], xtb[c * NN_ + jj], dot);
        float d = x2g + x2b[jj] - 2.f * dot;
        unsigned u = fkey(d);
        if (jj == il) u = 0xFFFFFFFFu;    // exclude self (strict max key)
        ud[s] = u;
        bool less = (u < min_hi) || (u == min_hi && (unsigned)jj < min_lo);
        min_hi = less ? u : min_hi;
        min_lo = less ? (unsigned)jj : min_lo;
    }

    // threshold M16 = 16th smallest lane-min
    unsigned bh = min_hi, bl = min_lo;
    bitonic64(bh, bl, lane);
    const unsigned m_hi = __shfl(bh, 15, 64);
    const unsigned m_lo = __shfl(bl, 15, 64);

    // count qualifying candidates per lane
    int c = 0;
#pragma unroll
    for (int s = 0; s < 32; ++s) {
        const unsigned jj = (unsigned)(s * 64 + lane);
        const unsigned u  = ud[s];
        bool q = (u < m_hi) || (u == m_hi && jj <= m_lo);
        c += q ? 1 : 0;
    }
    // exclusive prefix across lanes
    int pos = c;
#pragma unroll
    for (int m = 1; m < 64; m <<= 1) {
        int o = __shfl_up(pos, m, 64);
        if (lane >= m) pos += o;
    }
    const int total = __shfl(pos, 63, 64);
    pos -= c;

    if (total <= 64) {
        // compact to LDS (wave-private region; same-wave ds ordering via lgkmcnt)
#pragma unroll
        for (int s = 0; s < 32; ++s) {
            const unsigned jj = (unsigned)(s * 64 + lane);
            const unsigned u  = ud[s];
            bool q = (u < m_hi) || (u == m_hi && jj <= m_lo);
            if (q) { s_hi[wv][pos] = u; s_lo[wv][pos] = jj; pos++; }
        }
        unsigned u2 = (lane < total) ? s_hi[wv][lane] : 0xFFFFFFFFu;
        unsigned l2 = (lane < total) ? s_lo[wv][lane] : (0x80000000u + (unsigned)lane);
        bitonic64(u2, l2, lane);
        if (lane < KNN) {
            const int jglob = bb * NN_ + (int)l2;
            nbors[(size_t)g * KNN + lane] = jglob;
            atomicAdd(&indeg[jglob], 1);
        }
    } else {
        // exact fallback: 16 rounds of masked rescan + wave argmin (rare)
        unsigned taken = 0;
        for (int r = 0; r < KNN; ++r) {
            unsigned b_hi = 0xFFFFFFFFu, b_lo = 0xFFFFFFFFu;
#pragma unroll
            for (int s = 0; s < 32; ++s) {
                const unsigned jj = (unsigned)(s * 64 + lane);
                const unsigned u  = ud[s];
                bool avail = ((taken >> s) & 1u) == 0u;
                bool less  = avail && ((u < b_hi) || (u == b_hi && jj < b_lo));
                b_hi = less ? u : b_hi;
                b_lo = less ? jj : b_lo;
            }
            unsigned w_hi = b_hi, w_lo = b_lo;
#pragma unroll
            for (int m = 32; m >= 1; m >>= 1) {
                unsigned oh = __shfl_xor(w_hi, m, 64);
                unsigned ol = __shfl_xor(w_lo, m, 64);
                bool less = (oh < w_hi) || (oh == w_hi && ol < w_lo);
                w_hi = less ? oh : w_hi;
                w_lo = less ? ol : w_lo;
            }
            if (b_hi == w_hi && b_lo == w_lo) {   // unique winner lane
                taken |= 1u << (b_lo >> 6);
                const int jglob = bb * NN_ + (int)w_lo;
                nbors[(size_t)g * KNN + r] = jglob;
                atomicAdd(&indeg[jglob], 1);
            }
        }
    }
}

// ---------------- exclusive scan over indeg (single block) ----------------
__global__ __launch_bounds__(1024) void scan_kernel(const int* __restrict__ indeg,
                                                    int* __restrict__ offs,
                                                    int* __restrict__ cursor) {
    __shared__ int part[1024];
    int t = threadIdx.x;
    int4 lv[8];
    int s = 0;
#pragma unroll
    for (int i = 0; i < 8; ++i) {
        lv[i] = ((const int4*)indeg)[t * 8 + i];
        s += lv[i].x + lv[i].y + lv[i].z + lv[i].w;
    }
    part[t] = s;
    __syncthreads();
    for (int d = 1; d < 1024; d <<= 1) {
        int add = (t >= d) ? part[t - d] : 0;
        __syncthreads();
        part[t] += add;
        __syncthreads();
    }
    int run = part[t] - s;
#pragma unroll
    for (int i = 0; i < 8; ++i) {
        int4 o;
        o.x = run; run += lv[i].x;
        o.y = run; run += lv[i].y;
        o.z = run; run += lv[i].z;
        o.w = run; run += lv[i].w;
        ((int4*)offs)[t * 8 + i]   = o;
        ((int4*)cursor)[t * 8 + i] = o;
    }
    if (t == 1023) offs[NNODES] = run;
}

// ---------------- fill reverse adjacency ----------------
__global__ __launch_bounds__(256) void fill_kernel(const int* __restrict__ nbors,
                                                   int* __restrict__ cursor,
                                                   int* __restrict__ rev) {
    int e = blockIdx.x * 256 + threadIdx.x;
    if (e >= NEDGES) return;
    int dst = nbors[e];
    int src = e >> 4;                 // KNN == 16
    int pos = atomicAdd(&cursor[dst], 1);
    rev[pos] = src;
}

// ---------------- fused aggregate + dual linear (+ReLU) ----------------
template<int CIN, int COUT, int GS, bool RELU>
__global__ __launch_bounds__(256) void layer_kernel(const float* __restrict__ in,
                                                    const float* __restrict__ wrel,
                                                    const float* __restrict__ wroot,
                                                    const float* __restrict__ bias,
                                                    const int* __restrict__ offs,
                                                    const int* __restrict__ rev,
                                                    float* __restrict__ out) {
    constexpr int NT = 8;                 // nodes per block
    __shared__ float s_ai[NT][CIN][2];    // [0]=agg, [1]=own row
    const int j0 = blockIdx.x * NT;
    const int t  = threadIdx.x;

    constexpr int NG = 256 / GS;
    const int grp = t / GS, cc = t % GS;
    for (int nt = grp; nt < NT; nt += NG) {
        const int j = j0 + nt;
        if (cc < CIN) s_ai[nt][cc][1] = in[(size_t)j * CIN + cc];
        float agg = 0.f;
        const int e0 = offs[j], e1 = offs[j + 1];
        for (int e = e0; e < e1; ++e) {
            const int s = rev[e];
            if (cc < CIN) agg += in[(size_t)s * CIN + cc];
        }
        if (cc < CIN) s_ai[nt][cc][0] = agg;
    }
    __syncthreads();

    constexpr int REP = 256 / COUT;
    constexpr int NPT = NT / REP;
    const int c = t % COUT, r = t / COUT;
    float acc[NPT];
#pragma unroll
    for (int u = 0; u < NPT; ++u) acc[u] = bias[c];
#pragma unroll 4
    for (int k = 0; k < CIN; ++k) {
        const float wrv = wrel[k * COUT + c];
        const float wov = wroot[k * COUT + c];
#pragma unroll
        for (int u = 0; u < NPT; ++u) {
            const int nt = r + u * REP;
            acc[u] = fmaf(s_ai[nt][k][0], wrv, acc[u]);
            acc[u] = fmaf(s_ai[nt][k][1], wov, acc[u]);
        }
    }
#pragma unroll
    for (int u = 0; u < NPT; ++u) {
        const int nt = r + u * REP;
        float v = acc[u];
        if (RELU) v = fmaxf(v, 0.f);
        out[(size_t)(j0 + nt) * COUT + c] = v;
    }
}

// ---------------- final bilinear: out[b,i,j] = dot64(h[b,i], h[b,j]) ----------------
// 128x128 block tile, 8x8 per-thread register tile, k chunked 2x32.
// k-major LDS tiles; gap-insert swizzle (idx = j + j/32) kills the 4-way
// bank conflict of stride-32B b128 reads within a row.
#define EIDX(j) ((j) + ((j) >> 5))
__global__ __launch_bounds__(256) void edge_kernel(const float* __restrict__ h,
                                                   float* __restrict__ out) {
    __shared__ float tI[32][132];   // [k][EIDX(i)]
    __shared__ float tJ[32][132];   // [k][EIDX(j)]
    const int b  = blockIdx.z;
    const int i0 = blockIdx.y * 128;
    const int j0 = blockIdx.x * 128;
    const float* hb = h + (size_t)b * NN_ * 64;
    const int t = threadIdx.x;

    float acc[8][8];
#pragma unroll
    for (int u = 0; u < 8; ++u)
#pragma unroll
        for (int v = 0; v < 8; ++v) acc[u][v] = 0.f;

    const int ti = (t >> 4) * 8;      // 0..120
    const int tj = (t & 15) * 8;      // 0..120
    const int sr = t >> 1;            // staging row 0..127
    const int sg = (t & 1) * 16;      // staging k-segment

    for (int kc = 0; kc < 2; ++kc) {
        if (kc) __syncthreads();
        // stage 128 rows x 32 k each, transposed to k-major
        {
            const float* srcI = hb + (size_t)(i0 + sr) * 64 + kc * 32 + sg;
            const float* srcJ = hb + (size_t)(j0 + sr) * 64 + kc * 32 + sg;
            const int ri = EIDX(sr);
#pragma unroll
            for (int v = 0; v < 4; ++v) {
                float4 fi = *(const float4*)(srcI + v * 4);
                float4 fj = *(const float4*)(srcJ + v * 4);
                const int c = sg + v * 4;
                tI[c + 0][ri] = fi.x; tI[c + 1][ri] = fi.y;
                tI[c + 2][ri] = fi.z; tI[c + 3][ri] = fi.w;
                tJ[c + 0][ri] = fj.x; tJ[c + 1][ri] = fj.y;
                tJ[c + 2][ri] = fj.z; tJ[c + 3][ri] = fj.w;
            }
        }
        __syncthreads();

        const int ia = EIDX(ti), ja = EIDX(tj);
#pragma unroll 4
        for (int k = 0; k < 32; ++k) {
            float4 a0 = *(const float4*)(&tI[k][ia]);
            float4 a1 = *(const float4*)(&tI[k][ia + 4]);
            float4 b0 = *(const float4*)(&tJ[k][ja]);
            float4 b1 = *(const float4*)(&tJ[k][ja + 4]);
            float av[8] = {a0.x, a0.y, a0.z, a0.w, a1.x, a1.y, a1.z, a1.w};
            float bv[8] = {b0.x, b0.y, b0.z, b0.w, b1.x, b1.y, b1.z, b1.w};
#pragma unroll
            for (int u = 0; u < 8; ++u)
#pragma unroll
                for (int v = 0; v < 8; ++v) acc[u][v] = fmaf(av[u], bv[v], acc[u][v]);
        }
    }

#pragma unroll
    for (int u = 0; u < 8; ++u) {
        float* dst = out + ((size_t)b * NN_ + (i0 + ti + u)) * NN_ + (j0 + tj);
        float4 w0; w0.x = acc[u][0]; w0.y = acc[u][1]; w0.z = acc[u][2]; w0.w = acc[u][3];
        float4 w1; w1.x = acc[u][4]; w1.y = acc[u][5]; w1.z = acc[u][6]; w1.w = acc[u][7];
        *(float4*)(dst)     = w0;
        *(float4*)(dst + 4) = w1;
    }
}

extern "C" void kernel_launch(void* const* d_in, const int* in_sizes, int n_in,
                              void* d_out, int out_size, void* d_ws, size_t ws_size,
                              hipStream_t stream) {
    (void)in_sizes; (void)n_in; (void)out_size; (void)ws_size;
    const float* x = (const float*)d_in[0];
    const float* wr[4] = {(const float*)d_in[1],  (const float*)d_in[4],
                          (const float*)d_in[7],  (const float*)d_in[10]};
    const float* wo[4] = {(const float*)d_in[2],  (const float*)d_in[5],
                          (const float*)d_in[8],  (const float*)d_in[11]};
    const float* bs[4] = {(const float*)d_in[3],  (const float*)d_in[6],
                          (const float*)d_in[9],  (const float*)d_in[12]};
    float* out = (float*)d_out;

    char* w = (char*)d_ws;
    size_t o = 0;
    auto alloc = [&](size_t bytes) { void* p = w + o; o = (o + bytes + 255) & ~(size_t)255; return p; };
    int*   nbors  = (int*)  alloc((size_t)NEDGES * 4);
    int*   indeg  = (int*)  alloc((size_t)NNODES * 4);
    int*   offs   = (int*)  alloc((size_t)(NNODES + 1) * 4);
    int*   cursor = (int*)  alloc((size_t)NNODES * 4);
    int*   rev    = (int*)  alloc((size_t)NEDGES * 4);
    float* x2     = (float*)alloc((size_t)NNODES * 4);
    float* xt     = (float*)alloc((size_t)NNODES * CDIM * 4);
    float* hA     = (float*)alloc((size_t)NNODES * 128 * 4);
    float* hB     = (float*)alloc((size_t)NNODES * 128 * 4);

    prep_kernel<<<NNODES / 256, 256, 0, stream>>>(x, x2, xt, indeg);
    knn_kernel<<<NNODES / 8, 512, 0, stream>>>(x, xt, x2, nbors, indeg);
    scan_kernel<<<1, 1024, 0, stream>>>(indeg, offs, cursor);
    fill_kernel<<<NEDGES / 256, 256, 0, stream>>>(nbors, cursor, rev);

    layer_kernel<CDIM, 128, 16,  true ><<<NNODES / 8, 256, 0, stream>>>(x,  wr[0], wo[0], bs[0], offs, rev, hA);
    layer_kernel<128,  128, 128, true ><<<NNODES / 8, 256, 0, stream>>>(hA, wr[1], wo[1], bs[1], offs, rev, hB);
    layer_kernel<128,  128, 128, true ><<<NNODES / 8, 256, 0, stream>>>(hB, wr[2], wo[2], bs[2], offs, rev, hA);
    layer_kernel<128,  64,  128, false><<<NNODES / 8, 256, 0, stream>>>(hA, wr[3], wo[3], bs[3], offs, rev, hB);

    edge_kernel<<<dim3(16, 16, 16), 256, 0, stream>>>(hB, out);
}

// Round 2
// 947.907 us; speedup vs baseline: 1.1335x; 1.1335x over previous
//
#include <hip/hip_runtime.h>
#include <math.h>

#define BB_   16
#define NN_   2048
#define CDIM  10
#define KNN   16
#define NNODES (BB_*NN_)      // 32768
#define NEDGES (NNODES*KNN)   // 524288

// ---------------- prep: squared norms + zero indeg + SoA transpose ----------------
// xt[b][c][j] = x[b][j][c]  (c-plane writes are lane-coalesced)
__global__ __launch_bounds__(256) void prep_kernel(const float* __restrict__ x,
                                                   float* __restrict__ x2,
                                                   float* __restrict__ xt,
                                                   int* __restrict__ indeg) {
    int g = blockIdx.x * 256 + threadIdx.x;
    if (g >= NNODES) return;
    const int bb = g >> 11;
    const int j  = g & (NN_ - 1);
    const float* xr = x + (size_t)g * CDIM;
    float* xtb = xt + (size_t)bb * CDIM * NN_;
    float s = 0.f;
#pragma unroll
    for (int c = 0; c < CDIM; ++c) {
        float v = xr[c];
        s = fmaf(v, v, s);
        xtb[c * NN_ + j] = v;
    }
    x2[g] = s;
    indeg[g] = 0;
}

// order-preserving float->uint transform (handles negatives exactly)
__device__ __forceinline__ unsigned fkey(float f) {
    unsigned u = __float_as_uint(f);
    return ((int)u >= 0) ? (u ^ 0x80000000u) : ~u;
}

// full bitonic sort of (hi,lo) u64 keys across 64 lanes, ascending.
// keys MUST be unique (ties break permutation property).
__device__ __forceinline__ void bitonic64(unsigned& hi, unsigned& lo, int lane) {
#pragma unroll
    for (int k = 2; k <= 64; k <<= 1) {
#pragma unroll
        for (int j = k >> 1; j > 0; j >>= 1) {
            unsigned ohi = __shfl_xor(hi, j, 64);
            unsigned olo = __shfl_xor(lo, j, 64);
            bool up    = ((lane & k) == 0);
            bool lower = ((lane & j) == 0);
            bool oless = (ohi < hi) || (ohi == hi && olo < lo);  // other < mine
            bool take  = (lower == up) ? oless : !oless;
            hi = take ? ohi : hi;
            lo = take ? olo : lo;
        }
    }
}

// slot (0..31) <-> tile-local candidate index mapping:
//   slot = tile*16 + it*4 + q   <->   jj = tile*1024 + it*256 + 4*lane + q
__device__ __forceinline__ unsigned slot_to_jj(int slot, int lane) {
    return (unsigned)(((slot >> 4) << 10) + (((slot >> 2) & 3) << 8) + (lane << 2) + (slot & 3));
}

// ---------------- kNN: one wave per row, LDS-staged candidates ----------------
// Block = 8 waves = 8 rows of one batch. Candidates staged to LDS in 2 tiles
// of 1024: 11 SoA planes (10 coords + |xj|^2) = 44 KB. Distance pass reads
// float4-of-candidates per plane (ds_read_b128, banks 4l..4l+3 -> 8 beats =
// conflict-free minimum). Ranking key = |xj|^2 - 2*dot (drop the constant
// |xi|^2 -> identical ordering). Threshold-select as before.
__global__ __launch_bounds__(512) void knn_kernel(const float* __restrict__ x,
                                                  const float* __restrict__ xt,
                                                  const float* __restrict__ x2,
                                                  int* __restrict__ nbors,
                                                  int* __restrict__ indeg) {
    __shared__ __align__(16) float s_pl[11 * 1024];   // 44 KB candidate planes
    __shared__ unsigned s_hi[8][64];
    __shared__ unsigned s_lo[8][64];
    const int wv   = threadIdx.x >> 6;
    const int lane = threadIdx.x & 63;
    const int g  = blockIdx.x * 8 + wv;   // global row (node)
    const int bb = g >> 11;               // batch
    const int il = g & (NN_ - 1);         // local row index

    // own row (AoS, tiny)
    float xp[CDIM];
    const float* xr = x + (size_t)g * CDIM;
#pragma unroll
    for (int c = 0; c < CDIM; ++c) xp[c] = xr[c];

    const float* xtb = xt + (size_t)bb * CDIM * NN_;
    const float* x2b = x2 + bb * NN_;
    const float4* s_pl4 = (const float4*)s_pl;

    unsigned ud[32];
    unsigned min_hi = 0xFFFFFFFFu, min_lo = 0xFFFFFFFFu;

    for (int tile = 0; tile < 2; ++tile) {
        const int tb = tile << 10;
        __syncthreads();                 // previous tile fully consumed
        // stage 11 planes x 1024 candidates (coalesced: c constant per r)
        {
            const int t0 = threadIdx.x;
#pragma unroll
            for (int r = 0; r < 22; ++r) {
                const int idx = r * 512 + t0;
                const int c = idx >> 10;
                const int j = idx & 1023;
                s_pl[idx] = (c < 10) ? xtb[c * NN_ + tb + j] : x2b[tb + j];
            }
        }
        __syncthreads();
        // 4 groups of 256 candidates; lane handles 4 consecutive per group
#pragma unroll
        for (int it = 0; it < 4; ++it) {
            const int fo = it * 64 + lane;          // float4 offset within plane
            float4 dot = {0.f, 0.f, 0.f, 0.f};
#pragma unroll
            for (int c = 0; c < CDIM; ++c) {
                float4 v = s_pl4[c * 256 + fo];
                dot.x = fmaf(xp[c], v.x, dot.x);
                dot.y = fmaf(xp[c], v.y, dot.y);
                dot.z = fmaf(xp[c], v.z, dot.z);
                dot.w = fmaf(xp[c], v.w, dot.w);
            }
            const float4 xn = s_pl4[10 * 256 + fo];
            float kd[4];
            kd[0] = xn.x - 2.f * dot.x;
            kd[1] = xn.y - 2.f * dot.y;
            kd[2] = xn.z - 2.f * dot.z;
            kd[3] = xn.w - 2.f * dot.w;
            const int jbase = tb + it * 256 + (lane << 2);
#pragma unroll
            for (int q = 0; q < 4; ++q) {
                const int jj = jbase + q;
                unsigned u = fkey(kd[q]);
                if (jj == il) u = 0xFFFFFFFFu;      // exclude self
                ud[tile * 16 + it * 4 + q] = u;
                bool less = (u < min_hi) || (u == min_hi && (unsigned)jj < min_lo);
                min_hi = less ? u : min_hi;
                min_lo = less ? (unsigned)jj : min_lo;
            }
        }
    }

    // threshold M16 = 16th smallest lane-min
    unsigned bh = min_hi, bl = min_lo;
    bitonic64(bh, bl, lane);
    const unsigned m_hi = __shfl(bh, 15, 64);
    const unsigned m_lo = __shfl(bl, 15, 64);

    // count qualifying candidates per lane
    int c = 0;
#pragma unroll
    for (int slot = 0; slot < 32; ++slot) {
        const unsigned jj = slot_to_jj(slot, lane);
        const unsigned u  = ud[slot];
        bool q = (u < m_hi) || (u == m_hi && jj <= m_lo);
        c += q ? 1 : 0;
    }
    // exclusive prefix across lanes
    int pos = c;
#pragma unroll
    for (int m = 1; m < 64; m <<= 1) {
        int o = __shfl_up(pos, m, 64);
        if (lane >= m) pos += o;
    }
    const int total = __shfl(pos, 63, 64);
    pos -= c;

    if (total <= 64) {
        // compact to LDS (wave-private region; same-wave ds ordering via lgkmcnt)
#pragma unroll
        for (int slot = 0; slot < 32; ++slot) {
            const unsigned jj = slot_to_jj(slot, lane);
            const unsigned u  = ud[slot];
            bool q = (u < m_hi) || (u == m_hi && jj <= m_lo);
            if (q) { s_hi[wv][pos] = u; s_lo[wv][pos] = jj; pos++; }
        }
        unsigned u2 = (lane < total) ? s_hi[wv][lane] : 0xFFFFFFFFu;
        unsigned l2 = (lane < total) ? s_lo[wv][lane] : (0x80000000u + (unsigned)lane);
        bitonic64(u2, l2, lane);
        if (lane < KNN) {
            const int jglob = bb * NN_ + (int)l2;
            nbors[(size_t)g * KNN + lane] = jglob;
            atomicAdd(&indeg[jglob], 1);
        }
    } else {
        // exact fallback: 16 rounds of masked rescan + wave argmin (rare)
        unsigned taken = 0;
        for (int r = 0; r < KNN; ++r) {
            unsigned b_hi = 0xFFFFFFFFu, b_lo = 0xFFFFFFFFu;
#pragma unroll
            for (int slot = 0; slot < 32; ++slot) {
                const unsigned jj = slot_to_jj(slot, lane);
                const unsigned u  = ud[slot];
                bool avail = ((taken >> slot) & 1u) == 0u;
                bool less  = avail && ((u < b_hi) || (u == b_hi && jj < b_lo));
                b_hi = less ? u : b_hi;
                b_lo = less ? jj : b_lo;
            }
            unsigned w_hi = b_hi, w_lo = b_lo;
#pragma unroll
            for (int m = 32; m >= 1; m >>= 1) {
                unsigned oh = __shfl_xor(w_hi, m, 64);
                unsigned ol = __shfl_xor(w_lo, m, 64);
                bool less = (oh < w_hi) || (oh == w_hi && ol < w_lo);
                w_hi = less ? oh : w_hi;
                w_lo = less ? ol : w_lo;
            }
            if (b_hi == w_hi && b_lo == w_lo) {   // unique winner lane
                const int ws = ((int)(b_lo >> 10) << 4) + (((int)(b_lo >> 8) & 3) << 2) + (int)(b_lo & 3);
                taken |= 1u << ws;
                const int jglob = bb * NN_ + (int)w_lo;
                nbors[(size_t)g * KNN + r] = jglob;
                atomicAdd(&indeg[jglob], 1);
            }
        }
    }
}

// ---------------- exclusive scan over indeg (single block) ----------------
__global__ __launch_bounds__(1024) void scan_kernel(const int* __restrict__ indeg,
                                                    int* __restrict__ offs,
                                                    int* __restrict__ cursor) {
    __shared__ int part[1024];
    int t = threadIdx.x;
    int4 lv[8];
    int s = 0;
#pragma unroll
    for (int i = 0; i < 8; ++i) {
        lv[i] = ((const int4*)indeg)[t * 8 + i];
        s += lv[i].x + lv[i].y + lv[i].z + lv[i].w;
    }
    part[t] = s;
    __syncthreads();
    for (int d = 1; d < 1024; d <<= 1) {
        int add = (t >= d) ? part[t - d] : 0;
        __syncthreads();
        part[t] += add;
        __syncthreads();
    }
    int run = part[t] - s;
#pragma unroll
    for (int i = 0; i < 8; ++i) {
        int4 o;
        o.x = run; run += lv[i].x;
        o.y = run; run += lv[i].y;
        o.z = run; run += lv[i].z;
        o.w = run; run += lv[i].w;
        ((int4*)offs)[t * 8 + i]   = o;
        ((int4*)cursor)[t * 8 + i] = o;
    }
    if (t == 1023) offs[NNODES] = run;
}

// ---------------- fill reverse adjacency ----------------
__global__ __launch_bounds__(256) void fill_kernel(const int* __restrict__ nbors,
                                                   int* __restrict__ cursor,
                                                   int* __restrict__ rev) {
    int e = blockIdx.x * 256 + threadIdx.x;
    if (e >= NEDGES) return;
    int dst = nbors[e];
    int src = e >> 4;                 // KNN == 16
    int pos = atomicAdd(&cursor[dst], 1);
    rev[pos] = src;
}

// ---------------- fused aggregate + dual linear (+ReLU) ----------------
template<int CIN, int COUT, int GS, bool RELU>
__global__ __launch_bounds__(256) void layer_kernel(const float* __restrict__ in,
                                                    const float* __restrict__ wrel,
                                                    const float* __restrict__ wroot,
                                                    const float* __restrict__ bias,
                                                    const int* __restrict__ offs,
                                                    const int* __restrict__ rev,
                                                    float* __restrict__ out) {
    constexpr int NT = 8;                 // nodes per block
    __shared__ float s_ai[NT][CIN][2];    // [0]=agg, [1]=own row
    const int j0 = blockIdx.x * NT;
    const int t  = threadIdx.x;

    constexpr int NG = 256 / GS;
    const int grp = t / GS, cc = t % GS;
    for (int nt = grp; nt < NT; nt += NG) {
        const int j = j0 + nt;
        if (cc < CIN) s_ai[nt][cc][1] = in[(size_t)j * CIN + cc];
        float agg = 0.f;
        const int e0 = offs[j], e1 = offs[j + 1];
        for (int e = e0; e < e1; ++e) {
            const int s = rev[e];
            if (cc < CIN) agg += in[(size_t)s * CIN + cc];
        }
        if (cc < CIN) s_ai[nt][cc][0] = agg;
    }
    __syncthreads();

    constexpr int REP = 256 / COUT;
    constexpr int NPT = NT / REP;
    const int c = t % COUT, r = t / COUT;
    float acc[NPT];
#pragma unroll
    for (int u = 0; u < NPT; ++u) acc[u] = bias[c];
#pragma unroll 4
    for (int k = 0; k < CIN; ++k) {
        const float wrv = wrel[k * COUT + c];
        const float wov = wroot[k * COUT + c];
#pragma unroll
        for (int u = 0; u < NPT; ++u) {
            const int nt = r + u * REP;
            acc[u] = fmaf(s_ai[nt][k][0], wrv, acc[u]);
            acc[u] = fmaf(s_ai[nt][k][1], wov, acc[u]);
        }
    }
#pragma unroll
    for (int u = 0; u < NPT; ++u) {
        const int nt = r + u * REP;
        float v = acc[u];
        if (RELU) v = fmaxf(v, 0.f);
        out[(size_t)(j0 + nt) * COUT + c] = v;
    }
}

// ---------------- final bilinear: out[b,i,j] = dot64(h[b,i], h[b,j]) ----------------
// 128x128 block tile, 8x8 per-thread register tile, k chunked 2x32.
// k-major LDS tiles; gap-insert swizzle (idx = j + j/32) kills the 4-way
// bank conflict of stride-32B b128 reads within a row.
#define EIDX(j) ((j) + ((j) >> 5))
__global__ __launch_bounds__(256) void edge_kernel(const float* __restrict__ h,
                                                   float* __restrict__ out) {
    __shared__ float tI[32][132];   // [k][EIDX(i)]
    __shared__ float tJ[32][132];   // [k][EIDX(j)]
    const int b  = blockIdx.z;
    const int i0 = blockIdx.y * 128;
    const int j0 = blockIdx.x * 128;
    const float* hb = h + (size_t)b * NN_ * 64;
    const int t = threadIdx.x;

    float acc[8][8];
#pragma unroll
    for (int u = 0; u < 8; ++u)
#pragma unroll
        for (int v = 0; v < 8; ++v) acc[u][v] = 0.f;

    const int ti = (t >> 4) * 8;      // 0..120
    const int tj = (t & 15) * 8;      // 0..120
    const int sr = t >> 1;            // staging row 0..127
    const int sg = (t & 1) * 16;      // staging k-segment

    for (int kc = 0; kc < 2; ++kc) {
        if (kc) __syncthreads();
        // stage 128 rows x 32 k each, transposed to k-major
        {
            const float* srcI = hb + (size_t)(i0 + sr) * 64 + kc * 32 + sg;
            const float* srcJ = hb + (size_t)(j0 + sr) * 64 + kc * 32 + sg;
            const int ri = EIDX(sr);
#pragma unroll
            for (int v = 0; v < 4; ++v) {
                float4 fi = *(const float4*)(srcI + v * 4);
                float4 fj = *(const float4*)(srcJ + v * 4);
                const int c = sg + v * 4;
                tI[c + 0][ri] = fi.x; tI[c + 1][ri] = fi.y;
                tI[c + 2][ri] = fi.z; tI[c + 3][ri] = fi.w;
                tJ[c + 0][ri] = fj.x; tJ[c + 1][ri] = fj.y;
                tJ[c + 2][ri] = fj.z; tJ[c + 3][ri] = fj.w;
            }
        }
        __syncthreads();

        const int ia = EIDX(ti), ja = EIDX(tj);
#pragma unroll 4
        for (int k = 0; k < 32; ++k) {
            float4 a0 = *(const float4*)(&tI[k][ia]);
            float4 a1 = *(const float4*)(&tI[k][ia + 4]);
            float4 b0 = *(const float4*)(&tJ[k][ja]);
            float4 b1 = *(const float4*)(&tJ[k][ja + 4]);
            float av[8] = {a0.x, a0.y, a0.z, a0.w, a1.x, a1.y, a1.z, a1.w};
            float bv[8] = {b0.x, b0.y, b0.z, b0.w, b1.x, b1.y, b1.z, b1.w};
#pragma unroll
            for (int u = 0; u < 8; ++u)
#pragma unroll
                for (int v = 0; v < 8; ++v) acc[u][v] = fmaf(av[u], bv[v], acc[u][v]);
        }
    }

#pragma unroll
    for (int u = 0; u < 8; ++u) {
        float* dst = out + ((size_t)b * NN_ + (i0 + ti + u)) * NN_ + (j0 + tj);
        float4 w0; w0.x = acc[u][0]; w0.y = acc[u][1]; w0.z = acc[u][2]; w0.w = acc[u][3];
        float4 w1; w1.x = acc[u][4]; w1.y = acc[u][5]; w1.z = acc[u][6]; w1.w = acc[u][7];
        *(float4*)(dst)     = w0;
        *(float4*)(dst + 4) = w1;
    }
}

extern "C" void kernel_launch(void* const* d_in, const int* in_sizes, int n_in,
                              void* d_out, int out_size, void* d_ws, size_t ws_size,
                              hipStream_t stream) {
    (void)in_sizes; (void)n_in; (void)out_size; (void)ws_size;
    const float* x = (const float*)d_in[0];
    const float* wr[4] = {(const float*)d_in[1],  (const float*)d_in[4],
                          (const float*)d_in[7],  (const float*)d_in[10]};
    const float* wo[4] = {(const float*)d_in[2],  (const float*)d_in[5],
                          (const float*)d_in[8],  (const float*)d_in[11]};
    const float* bs[4] = {(const float*)d_in[3],  (const float*)d_in[6],
                          (const float*)d_in[9],  (const float*)d_in[12]};
    float* out = (float*)d_out;

    char* w = (char*)d_ws;
    size_t o = 0;
    auto alloc = [&](size_t bytes) { void* p = w + o; o = (o + bytes + 255) & ~(size_t)255; return p; };
    int*   nbors  = (int*)  alloc((size_t)NEDGES * 4);
    int*   indeg  = (int*)  alloc((size_t)NNODES * 4);
    int*   offs   = (int*)  alloc((size_t)(NNODES + 1) * 4);
    int*   cursor = (int*)  alloc((size_t)NNODES * 4);
    int*   rev    = (int*)  alloc((size_t)NEDGES * 4);
    float* x2     = (float*)alloc((size_t)NNODES * 4);
    float* xt     = (float*)alloc((size_t)NNODES * CDIM * 4);
    float* hA     = (float*)alloc((size_t)NNODES * 128 * 4);
    float* hB     = (float*)alloc((size_t)NNODES * 128 * 4);

    prep_kernel<<<NNODES / 256, 256, 0, stream>>>(x, x2, xt, indeg);
    knn_kernel<<<NNODES / 8, 512, 0, stream>>>(x, xt, x2, nbors, indeg);
    scan_kernel<<<1, 1024, 0, stream>>>(indeg, offs, cursor);
    fill_kernel<<<NEDGES / 256, 256, 0, stream>>>(nbors, cursor, rev);

    layer_kernel<CDIM, 128, 16,  true ><<<NNODES / 8, 256, 0, stream>>>(x,  wr[0], wo[0], bs[0], offs, rev, hA);
    layer_kernel<128,  128, 128, true ><<<NNODES / 8, 256, 0, stream>>>(hA, wr[1], wo[1], bs[1], offs, rev, hB);
    layer_kernel<128,  128, 128, true ><<<NNODES / 8, 256, 0, stream>>>(hB, wr[2], wo[2], bs[2], offs, rev, hA);
    layer_kernel<128,  64,  128, false><<<NNODES / 8, 256, 0, stream>>>(hA, wr[3], wo[3], bs[3], offs, rev, hB);

    edge_kernel<<<dim3(16, 16, 16), 256, 0, stream>>>(hB, out);
}

// Round 3
// 755.733 us; speedup vs baseline: 1.4217x; 1.2543x over previous
//
#include <hip/hip_runtime.h>
#include <math.h>

#define BB_   16
#define NN_   2048
#define CDIM  10
#define KNN   16
#define NNODES (BB_*NN_)      // 32768
#define NEDGES (NNODES*KNN)   // 524288

// ---------------- prep: squared norms + zero indeg + SoA transpose ----------------
// xt[b][c][j] = x[b][j][c]  (c-plane writes are lane-coalesced)
__global__ __launch_bounds__(256) void prep_kernel(const float* __restrict__ x,
                                                   float* __restrict__ x2,
                                                   float* __restrict__ xt,
                                                   int* __restrict__ indeg) {
    int g = blockIdx.x * 256 + threadIdx.x;
    if (g >= NNODES) return;
    const int bb = g >> 11;
    const int j  = g & (NN_ - 1);
    const float* xr = x + (size_t)g * CDIM;
    float* xtb = xt + (size_t)bb * CDIM * NN_;
    float s = 0.f;
#pragma unroll
    for (int c = 0; c < CDIM; ++c) {
        float v = xr[c];
        s = fmaf(v, v, s);
        xtb[c * NN_ + j] = v;
    }
    x2[g] = s;
    indeg[g] = 0;
}

// order-preserving float->uint transform (handles negatives exactly)
__device__ __forceinline__ unsigned fkey(float f) {
    unsigned u = __float_as_uint(f);
    return ((int)u >= 0) ? (u ^ 0x80000000u) : ~u;
}

// full bitonic sort of (hi,lo) u64 keys across 64 lanes, ascending.
// keys MUST be unique (ties break permutation property).
__device__ __forceinline__ void bitonic64(unsigned& hi, unsigned& lo, int lane) {
#pragma unroll
    for (int k = 2; k <= 64; k <<= 1) {
#pragma unroll
        for (int j = k >> 1; j > 0; j >>= 1) {
            unsigned ohi = __shfl_xor(hi, j, 64);
            unsigned olo = __shfl_xor(lo, j, 64);
            bool up    = ((lane & k) == 0);
            bool lower = ((lane & j) == 0);
            bool oless = (ohi < hi) || (ohi == hi && olo < lo);  // other < mine
            bool take  = (lower == up) ? oless : !oless;
            hi = take ? ohi : hi;
            lo = take ? olo : lo;
        }
    }
}

// slot (0..31) <-> tile-local candidate index mapping:
//   slot = tile*16 + it*4 + q   <->   jj = tile*1024 + it*256 + 4*lane + q
__device__ __forceinline__ unsigned slot_to_jj(int slot, int lane) {
    return (unsigned)(((slot >> 4) << 10) + (((slot >> 2) & 3) << 8) + (lane << 2) + (slot & 3));
}

// ---------------- kNN: one wave per row, LDS-staged candidates ----------------
__global__ __launch_bounds__(512) void knn_kernel(const float* __restrict__ x,
                                                  const float* __restrict__ xt,
                                                  const float* __restrict__ x2,
                                                  int* __restrict__ nbors,
                                                  int* __restrict__ indeg) {
    __shared__ __align__(16) float s_pl[11 * 1024];   // 44 KB candidate planes
    __shared__ unsigned s_hi[8][64];
    __shared__ unsigned s_lo[8][64];
    const int wv   = threadIdx.x >> 6;
    const int lane = threadIdx.x & 63;
    const int g  = blockIdx.x * 8 + wv;   // global row (node)
    const int bb = g >> 11;               // batch
    const int il = g & (NN_ - 1);         // local row index

    // own row (AoS, tiny)
    float xp[CDIM];
    const float* xr = x + (size_t)g * CDIM;
#pragma unroll
    for (int c = 0; c < CDIM; ++c) xp[c] = xr[c];

    const float* xtb = xt + (size_t)bb * CDIM * NN_;
    const float* x2b = x2 + bb * NN_;
    const float4* s_pl4 = (const float4*)s_pl;

    unsigned ud[32];
    unsigned min_hi = 0xFFFFFFFFu, min_lo = 0xFFFFFFFFu;

    for (int tile = 0; tile < 2; ++tile) {
        const int tb = tile << 10;
        __syncthreads();                 // previous tile fully consumed
        // stage 11 planes x 1024 candidates (coalesced: c constant per r)
        {
            const int t0 = threadIdx.x;
#pragma unroll
            for (int r = 0; r < 22; ++r) {
                const int idx = r * 512 + t0;
                const int c = idx >> 10;
                const int j = idx & 1023;
                s_pl[idx] = (c < 10) ? xtb[c * NN_ + tb + j] : x2b[tb + j];
            }
        }
        __syncthreads();
        // 4 groups of 256 candidates; lane handles 4 consecutive per group
#pragma unroll
        for (int it = 0; it < 4; ++it) {
            const int fo = it * 64 + lane;          // float4 offset within plane
            float4 dot = {0.f, 0.f, 0.f, 0.f};
#pragma unroll
            for (int c = 0; c < CDIM; ++c) {
                float4 v = s_pl4[c * 256 + fo];
                dot.x = fmaf(xp[c], v.x, dot.x);
                dot.y = fmaf(xp[c], v.y, dot.y);
                dot.z = fmaf(xp[c], v.z, dot.z);
                dot.w = fmaf(xp[c], v.w, dot.w);
            }
            const float4 xn = s_pl4[10 * 256 + fo];
            float kd[4];
            kd[0] = xn.x - 2.f * dot.x;
            kd[1] = xn.y - 2.f * dot.y;
            kd[2] = xn.z - 2.f * dot.z;
            kd[3] = xn.w - 2.f * dot.w;
            const int jbase = tb + it * 256 + (lane << 2);
#pragma unroll
            for (int q = 0; q < 4; ++q) {
                const int jj = jbase + q;
                unsigned u = fkey(kd[q]);
                if (jj == il) u = 0xFFFFFFFFu;      // exclude self
                ud[tile * 16 + it * 4 + q] = u;
                bool less = (u < min_hi) || (u == min_hi && (unsigned)jj < min_lo);
                min_hi = less ? u : min_hi;
                min_lo = less ? (unsigned)jj : min_lo;
            }
        }
    }

    // threshold M16 = 16th smallest lane-min
    unsigned bh = min_hi, bl = min_lo;
    bitonic64(bh, bl, lane);
    const unsigned m_hi = __shfl(bh, 15, 64);
    const unsigned m_lo = __shfl(bl, 15, 64);

    // count qualifying candidates per lane
    int c = 0;
#pragma unroll
    for (int slot = 0; slot < 32; ++slot) {
        const unsigned jj = slot_to_jj(slot, lane);
        const unsigned u  = ud[slot];
        bool q = (u < m_hi) || (u == m_hi && jj <= m_lo);
        c += q ? 1 : 0;
    }
    // exclusive prefix across lanes
    int pos = c;
#pragma unroll
    for (int m = 1; m < 64; m <<= 1) {
        int o = __shfl_up(pos, m, 64);
        if (lane >= m) pos += o;
    }
    const int total = __shfl(pos, 63, 64);
    pos -= c;

    if (total <= 64) {
        // compact to LDS (wave-private region; same-wave ds ordering via lgkmcnt)
#pragma unroll
        for (int slot = 0; slot < 32; ++slot) {
            const unsigned jj = slot_to_jj(slot, lane);
            const unsigned u  = ud[slot];
            bool q = (u < m_hi) || (u == m_hi && jj <= m_lo);
            if (q) { s_hi[wv][pos] = u; s_lo[wv][pos] = jj; pos++; }
        }
        unsigned u2 = (lane < total) ? s_hi[wv][lane] : 0xFFFFFFFFu;
        unsigned l2 = (lane < total) ? s_lo[wv][lane] : (0x80000000u + (unsigned)lane);
        bitonic64(u2, l2, lane);
        if (lane < KNN) {
            const int jglob = bb * NN_ + (int)l2;
            nbors[(size_t)g * KNN + lane] = jglob;
            atomicAdd(&indeg[jglob], 1);
        }
    } else {
        // exact fallback: 16 rounds of masked rescan + wave argmin (rare)
        unsigned taken = 0;
        for (int r = 0; r < KNN; ++r) {
            unsigned b_hi = 0xFFFFFFFFu, b_lo = 0xFFFFFFFFu;
#pragma unroll
            for (int slot = 0; slot < 32; ++slot) {
                const unsigned jj = slot_to_jj(slot, lane);
                const unsigned u  = ud[slot];
                bool avail = ((taken >> slot) & 1u) == 0u;
                bool less  = avail && ((u < b_hi) || (u == b_hi && jj < b_lo));
                b_hi = less ? u : b_hi;
                b_lo = less ? jj : b_lo;
            }
            unsigned w_hi = b_hi, w_lo = b_lo;
#pragma unroll
            for (int m = 32; m >= 1; m >>= 1) {
                unsigned oh = __shfl_xor(w_hi, m, 64);
                unsigned ol = __shfl_xor(w_lo, m, 64);
                bool less = (oh < w_hi) || (oh == w_hi && ol < w_lo);
                w_hi = less ? oh : w_hi;
                w_lo = less ? ol : w_lo;
            }
            if (b_hi == w_hi && b_lo == w_lo) {   // unique winner lane
                const int ws = ((int)(b_lo >> 10) << 4) + (((int)(b_lo >> 8) & 3) << 2) + (int)(b_lo & 3);
                taken |= 1u << ws;
                const int jglob = bb * NN_ + (int)w_lo;
                nbors[(size_t)g * KNN + r] = jglob;
                atomicAdd(&indeg[jglob], 1);
            }
        }
    }
}

// ---------------- exclusive scan over indeg (single block) ----------------
__global__ __launch_bounds__(1024) void scan_kernel(const int* __restrict__ indeg,
                                                    int* __restrict__ offs,
                                                    int* __restrict__ cursor) {
    __shared__ int part[1024];
    int t = threadIdx.x;
    int4 lv[8];
    int s = 0;
#pragma unroll
    for (int i = 0; i < 8; ++i) {
        lv[i] = ((const int4*)indeg)[t * 8 + i];
        s += lv[i].x + lv[i].y + lv[i].z + lv[i].w;
    }
    part[t] = s;
    __syncthreads();
    for (int d = 1; d < 1024; d <<= 1) {
        int add = (t >= d) ? part[t - d] : 0;
        __syncthreads();
        part[t] += add;
        __syncthreads();
    }
    int run = part[t] - s;
#pragma unroll
    for (int i = 0; i < 8; ++i) {
        int4 o;
        o.x = run; run += lv[i].x;
        o.y = run; run += lv[i].y;
        o.z = run; run += lv[i].z;
        o.w = run; run += lv[i].w;
        ((int4*)offs)[t * 8 + i]   = o;
        ((int4*)cursor)[t * 8 + i] = o;
    }
    if (t == 1023) offs[NNODES] = run;
}

// ---------------- fill reverse adjacency ----------------
__global__ __launch_bounds__(256) void fill_kernel(const int* __restrict__ nbors,
                                                   int* __restrict__ cursor,
                                                   int* __restrict__ rev) {
    int e = blockIdx.x * 256 + threadIdx.x;
    if (e >= NEDGES) return;
    int dst = nbors[e];
    int src = e >> 4;                 // KNN == 16
    int pos = atomicAdd(&cursor[dst], 1);
    rev[pos] = src;
}

// ---------------- layer 1 (CIN=10): old per-channel path ----------------
template<int CIN, int COUT, int GS, bool RELU>
__global__ __launch_bounds__(256) void layer_kernel(const float* __restrict__ in,
                                                    const float* __restrict__ wrel,
                                                    const float* __restrict__ wroot,
                                                    const float* __restrict__ bias,
                                                    const int* __restrict__ offs,
                                                    const int* __restrict__ rev,
                                                    float* __restrict__ out) {
    constexpr int NT = 8;                 // nodes per block
    __shared__ float s_ai[NT][CIN][2];    // [0]=agg, [1]=own row
    const int j0 = blockIdx.x * NT;
    const int t  = threadIdx.x;

    constexpr int NG = 256 / GS;
    const int grp = t / GS, cc = t % GS;
    for (int nt = grp; nt < NT; nt += NG) {
        const int j = j0 + nt;
        if (cc < CIN) s_ai[nt][cc][1] = in[(size_t)j * CIN + cc];
        float agg = 0.f;
        const int e0 = offs[j], e1 = offs[j + 1];
        for (int e = e0; e < e1; ++e) {
            const int s = rev[e];
            if (cc < CIN) agg += in[(size_t)s * CIN + cc];
        }
        if (cc < CIN) s_ai[nt][cc][0] = agg;
    }
    __syncthreads();

    constexpr int REP = 256 / COUT;
    constexpr int NPT = NT / REP;
    const int c = t % COUT, r = t / COUT;
    float acc[NPT];
#pragma unroll
    for (int u = 0; u < NPT; ++u) acc[u] = bias[c];
#pragma unroll 4
    for (int k = 0; k < CIN; ++k) {
        const float wrv = wrel[k * COUT + c];
        const float wov = wroot[k * COUT + c];
#pragma unroll
        for (int u = 0; u < NPT; ++u) {
            const int nt = r + u * REP;
            acc[u] = fmaf(s_ai[nt][k][0], wrv, acc[u]);
            acc[u] = fmaf(s_ai[nt][k][1], wov, acc[u]);
        }
    }
#pragma unroll
    for (int u = 0; u < NPT; ++u) {
        const int nt = r + u * REP;
        float v = acc[u];
        if (RELU) v = fmaxf(v, 0.f);
        out[(size_t)(j0 + nt) * COUT + c] = v;
    }
}

// ---------------- layers 2-4 (CIN=128): mini-GEMM layer ----------------
// NT=32 nodes/block. Stage: 8 parallel node-groups x 32 lanes x float4
// (vector gather, 4 independent partials -> 4 loads in flight). GEMM:
// thread = (4-col group x NPN nodes); k chunked by 4: broadcast
// ds_read_b128 A-reads + L1-resident float4 weight reads; 128 FMAs per
// chunk per 10 mem instrs (vs 1:1 in the old per-channel path).
template<int COUT, bool RELU>
__global__ __launch_bounds__(256) void layer_big_kernel(const float* __restrict__ in,
                                                        const float* __restrict__ wrel,
                                                        const float* __restrict__ wroot,
                                                        const float* __restrict__ bias,
                                                        const int* __restrict__ offs,
                                                        const int* __restrict__ rev,
                                                        float* __restrict__ out) {
    constexpr int CIN = 128;
    constexpr int NT  = 32;               // nodes per block
    __shared__ float s_agg[NT][CIN];      // 16 KB
    __shared__ float s_own[NT][CIN];      // 16 KB
    const int j0 = blockIdx.x * NT;
    const int t  = threadIdx.x;

    // ---- stage: 8 node-groups in parallel, float4 per lane ----
    {
        const int ng  = t >> 5;           // 0..7
        const int c4  = (t & 31) * 4;     // channel group
#pragma unroll
        for (int r = 0; r < NT / 8; ++r) {
            const int nt = r * 8 + ng;
            const int j  = j0 + nt;
            float4 own = *(const float4*)(in + (size_t)j * CIN + c4);
            float4 a0 = {0.f,0.f,0.f,0.f}, a1 = a0, a2 = a0, a3 = a0;
            const int e0 = offs[j], e1 = offs[j + 1];
            int e = e0;
            for (; e + 4 <= e1; e += 4) {
                const int s0 = rev[e], s1 = rev[e+1], s2 = rev[e+2], s3 = rev[e+3];
                float4 v0 = *(const float4*)(in + (size_t)s0 * CIN + c4);
                float4 v1 = *(const float4*)(in + (size_t)s1 * CIN + c4);
                float4 v2 = *(const float4*)(in + (size_t)s2 * CIN + c4);
                float4 v3 = *(const float4*)(in + (size_t)s3 * CIN + c4);
                a0.x += v0.x; a0.y += v0.y; a0.z += v0.z; a0.w += v0.w;
                a1.x += v1.x; a1.y += v1.y; a1.z += v1.z; a1.w += v1.w;
                a2.x += v2.x; a2.y += v2.y; a2.z += v2.z; a2.w += v2.w;
                a3.x += v3.x; a3.y += v3.y; a3.z += v3.z; a3.w += v3.w;
            }
            for (; e < e1; ++e) {
                const int s0 = rev[e];
                float4 v0 = *(const float4*)(in + (size_t)s0 * CIN + c4);
                a0.x += v0.x; a0.y += v0.y; a0.z += v0.z; a0.w += v0.w;
            }
            float4 agg;
            agg.x = (a0.x + a1.x) + (a2.x + a3.x);
            agg.y = (a0.y + a1.y) + (a2.y + a3.y);
            agg.z = (a0.z + a1.z) + (a2.z + a3.z);
            agg.w = (a0.w + a1.w) + (a2.w + a3.w);
            *(float4*)(&s_agg[nt][c4]) = agg;
            *(float4*)(&s_own[nt][c4]) = own;
        }
    }
    __syncthreads();

    // ---- GEMM: out[n][c] = agg.wrel + own.wroot + bias ----
    constexpr int CG  = COUT / 4;         // col groups (32 or 16)
    constexpr int NGG = 256 / CG;         // node groups (8 or 16)
    constexpr int NPN = NT / NGG;         // nodes per thread (4 or 2)
    const int cg = t % CG, ng = t / CG;
    const int c4 = cg * 4;
    const int nb = ng * NPN;

    float acc[NPN][4];
    {
        const float4 b4 = *(const float4*)(bias + c4);
#pragma unroll
        for (int u = 0; u < NPN; ++u) {
            acc[u][0] = b4.x; acc[u][1] = b4.y; acc[u][2] = b4.z; acc[u][3] = b4.w;
        }
    }

#pragma unroll 4
    for (int k4 = 0; k4 < CIN; k4 += 4) {
        float4 wr_[4], wo_[4];
#pragma unroll
        for (int kk = 0; kk < 4; ++kk) {
            wr_[kk] = *(const float4*)(wrel  + (size_t)(k4 + kk) * COUT + c4);
            wo_[kk] = *(const float4*)(wroot + (size_t)(k4 + kk) * COUT + c4);
        }
#pragma unroll
        for (int u = 0; u < NPN; ++u) {
            const int n = nb + u;
            float4 ag = *(const float4*)(&s_agg[n][k4]);
            float4 ow = *(const float4*)(&s_own[n][k4]);
            acc[u][0] = fmaf(ag.x, wr_[0].x, acc[u][0]); acc[u][0] = fmaf(ag.y, wr_[1].x, acc[u][0]);
            acc[u][0] = fmaf(ag.z, wr_[2].x, acc[u][0]); acc[u][0] = fmaf(ag.w, wr_[3].x, acc[u][0]);
            acc[u][0] = fmaf(ow.x, wo_[0].x, acc[u][0]); acc[u][0] = fmaf(ow.y, wo_[1].x, acc[u][0]);
            acc[u][0] = fmaf(ow.z, wo_[2].x, acc[u][0]); acc[u][0] = fmaf(ow.w, wo_[3].x, acc[u][0]);

            acc[u][1] = fmaf(ag.x, wr_[0].y, acc[u][1]); acc[u][1] = fmaf(ag.y, wr_[1].y, acc[u][1]);
            acc[u][1] = fmaf(ag.z, wr_[2].y, acc[u][1]); acc[u][1] = fmaf(ag.w, wr_[3].y, acc[u][1]);
            acc[u][1] = fmaf(ow.x, wo_[0].y, acc[u][1]); acc[u][1] = fmaf(ow.y, wo_[1].y, acc[u][1]);
            acc[u][1] = fmaf(ow.z, wo_[2].y, acc[u][1]); acc[u][1] = fmaf(ow.w, wo_[3].y, acc[u][1]);

            acc[u][2] = fmaf(ag.x, wr_[0].z, acc[u][2]); acc[u][2] = fmaf(ag.y, wr_[1].z, acc[u][2]);
            acc[u][2] = fmaf(ag.z, wr_[2].z, acc[u][2]); acc[u][2] = fmaf(ag.w, wr_[3].z, acc[u][2]);
            acc[u][2] = fmaf(ow.x, wo_[0].z, acc[u][2]); acc[u][2] = fmaf(ow.y, wo_[1].z, acc[u][2]);
            acc[u][2] = fmaf(ow.z, wo_[2].z, acc[u][2]); acc[u][2] = fmaf(ow.w, wo_[3].z, acc[u][2]);

            acc[u][3] = fmaf(ag.x, wr_[0].w, acc[u][3]); acc[u][3] = fmaf(ag.y, wr_[1].w, acc[u][3]);
            acc[u][3] = fmaf(ag.z, wr_[2].w, acc[u][3]); acc[u][3] = fmaf(ag.w, wr_[3].w, acc[u][3]);
            acc[u][3] = fmaf(ow.x, wo_[0].w, acc[u][3]); acc[u][3] = fmaf(ow.y, wo_[1].w, acc[u][3]);
            acc[u][3] = fmaf(ow.z, wo_[2].w, acc[u][3]); acc[u][3] = fmaf(ow.w, wo_[3].w, acc[u][3]);
        }
    }

#pragma unroll
    for (int u = 0; u < NPN; ++u) {
        const int j = j0 + nb + u;
        float4 v;
        v.x = acc[u][0]; v.y = acc[u][1]; v.z = acc[u][2]; v.w = acc[u][3];
        if (RELU) {
            v.x = fmaxf(v.x, 0.f); v.y = fmaxf(v.y, 0.f);
            v.z = fmaxf(v.z, 0.f); v.w = fmaxf(v.w, 0.f);
        }
        *(float4*)(out + (size_t)j * COUT + c4) = v;
    }
}

// ---------------- final bilinear: out[b,i,j] = dot64(h[b,i], h[b,j]) ----------------
#define EIDX(j) ((j) + ((j) >> 5))
__global__ __launch_bounds__(256) void edge_kernel(const float* __restrict__ h,
                                                   float* __restrict__ out) {
    __shared__ float tI[32][132];   // [k][EIDX(i)]
    __shared__ float tJ[32][132];   // [k][EIDX(j)]
    const int b  = blockIdx.z;
    const int i0 = blockIdx.y * 128;
    const int j0 = blockIdx.x * 128;
    const float* hb = h + (size_t)b * NN_ * 64;
    const int t = threadIdx.x;

    float acc[8][8];
#pragma unroll
    for (int u = 0; u < 8; ++u)
#pragma unroll
        for (int v = 0; v < 8; ++v) acc[u][v] = 0.f;

    const int ti = (t >> 4) * 8;      // 0..120
    const int tj = (t & 15) * 8;      // 0..120
    const int sr = t >> 1;            // staging row 0..127
    const int sg = (t & 1) * 16;      // staging k-segment

    for (int kc = 0; kc < 2; ++kc) {
        if (kc) __syncthreads();
        // stage 128 rows x 32 k each, transposed to k-major
        {
            const float* srcI = hb + (size_t)(i0 + sr) * 64 + kc * 32 + sg;
            const float* srcJ = hb + (size_t)(j0 + sr) * 64 + kc * 32 + sg;
            const int ri = EIDX(sr);
#pragma unroll
            for (int v = 0; v < 4; ++v) {
                float4 fi = *(const float4*)(srcI + v * 4);
                float4 fj = *(const float4*)(srcJ + v * 4);
                const int c = sg + v * 4;
                tI[c + 0][ri] = fi.x; tI[c + 1][ri] = fi.y;
                tI[c + 2][ri] = fi.z; tI[c + 3][ri] = fi.w;
                tJ[c + 0][ri] = fj.x; tJ[c + 1][ri] = fj.y;
                tJ[c + 2][ri] = fj.z; tJ[c + 3][ri] = fj.w;
            }
        }
        __syncthreads();

        const int ia = EIDX(ti), ja = EIDX(tj);
#pragma unroll 4
        for (int k = 0; k < 32; ++k) {
            float4 a0 = *(const float4*)(&tI[k][ia]);
            float4 a1 = *(const float4*)(&tI[k][ia + 4]);
            float4 b0 = *(const float4*)(&tJ[k][ja]);
            float4 b1 = *(const float4*)(&tJ[k][ja + 4]);
            float av[8] = {a0.x, a0.y, a0.z, a0.w, a1.x, a1.y, a1.z, a1.w};
            float bv[8] = {b0.x, b0.y, b0.z, b0.w, b1.x, b1.y, b1.z, b1.w};
#pragma unroll
            for (int u = 0; u < 8; ++u)
#pragma unroll
                for (int v = 0; v < 8; ++v) acc[u][v] = fmaf(av[u], bv[v], acc[u][v]);
        }
    }

#pragma unroll
    for (int u = 0; u < 8; ++u) {
        float* dst = out + ((size_t)b * NN_ + (i0 + ti + u)) * NN_ + (j0 + tj);
        float4 w0; w0.x = acc[u][0]; w0.y = acc[u][1]; w0.z = acc[u][2]; w0.w = acc[u][3];
        float4 w1; w1.x = acc[u][4]; w1.y = acc[u][5]; w1.z = acc[u][6]; w1.w = acc[u][7];
        *(float4*)(dst)     = w0;
        *(float4*)(dst + 4) = w1;
    }
}

extern "C" void kernel_launch(void* const* d_in, const int* in_sizes, int n_in,
                              void* d_out, int out_size, void* d_ws, size_t ws_size,
                              hipStream_t stream) {
    (void)in_sizes; (void)n_in; (void)out_size; (void)ws_size;
    const float* x = (const float*)d_in[0];
    const float* wr[4] = {(const float*)d_in[1],  (const float*)d_in[4],
                          (const float*)d_in[7],  (const float*)d_in[10]};
    const float* wo[4] = {(const float*)d_in[2],  (const float*)d_in[5],
                          (const float*)d_in[8],  (const float*)d_in[11]};
    const float* bs[4] = {(const float*)d_in[3],  (const float*)d_in[6],
                          (const float*)d_in[9],  (const float*)d_in[12]};
    float* out = (float*)d_out;

    char* w = (char*)d_ws;
    size_t o = 0;
    auto alloc = [&](size_t bytes) { void* p = w + o; o = (o + bytes + 255) & ~(size_t)255; return p; };
    int*   nbors  = (int*)  alloc((size_t)NEDGES * 4);
    int*   indeg  = (int*)  alloc((size_t)NNODES * 4);
    int*   offs   = (int*)  alloc((size_t)(NNODES + 1) * 4);
    int*   cursor = (int*)  alloc((size_t)NNODES * 4);
    int*   rev    = (int*)  alloc((size_t)NEDGES * 4);
    float* x2     = (float*)alloc((size_t)NNODES * 4);
    float* xt     = (float*)alloc((size_t)NNODES * CDIM * 4);
    float* hA     = (float*)alloc((size_t)NNODES * 128 * 4);
    float* hB     = (float*)alloc((size_t)NNODES * 128 * 4);

    prep_kernel<<<NNODES / 256, 256, 0, stream>>>(x, x2, xt, indeg);
    knn_kernel<<<NNODES / 8, 512, 0, stream>>>(x, xt, x2, nbors, indeg);
    scan_kernel<<<1, 1024, 0, stream>>>(indeg, offs, cursor);
    fill_kernel<<<NEDGES / 256, 256, 0, stream>>>(nbors, cursor, rev);

    layer_kernel<CDIM, 128, 16, true ><<<NNODES / 8, 256, 0, stream>>>(x,  wr[0], wo[0], bs[0], offs, rev, hA);
    layer_big_kernel<128, true ><<<NNODES / 32, 256, 0, stream>>>(hA, wr[1], wo[1], bs[1], offs, rev, hB);
    layer_big_kernel<128, true ><<<NNODES / 32, 256, 0, stream>>>(hB, wr[2], wo[2], bs[2], offs, rev, hA);
    layer_big_kernel<64,  false><<<NNODES / 32, 256, 0, stream>>>(hA, wr[3], wo[3], bs[3], offs, rev, hB);

    edge_kernel<<<dim3(16, 16, 16), 256, 0, stream>>>(hB, out);
}

// Round 4
// 741.153 us; speedup vs baseline: 1.4497x; 1.0197x over previous
//
#include <hip/hip_runtime.h>
#include <math.h>

#define BB_   16
#define NN_   2048
#define CDIM  10
#define KNN   16
#define NNODES (BB_*NN_)      // 32768
#define NEDGES (NNODES*KNN)   // 524288

// ---------------- prep: squared norms + zero indeg + SoA transpose ----------------
// xt[b][c][j] = x[b][j][c]  (c-plane writes are lane-coalesced)
__global__ __launch_bounds__(256) void prep_kernel(const float* __restrict__ x,
                                                   float* __restrict__ x2,
                                                   float* __restrict__ xt,
                                                   int* __restrict__ indeg) {
    int g = blockIdx.x * 256 + threadIdx.x;
    if (g >= NNODES) return;
    const int bb = g >> 11;
    const int j  = g & (NN_ - 1);
    const float* xr = x + (size_t)g * CDIM;
    float* xtb = xt + (size_t)bb * CDIM * NN_;
    float s = 0.f;
#pragma unroll
    for (int c = 0; c < CDIM; ++c) {
        float v = xr[c];
        s = fmaf(v, v, s);
        xtb[c * NN_ + j] = v;
    }
    x2[g] = s;
    indeg[g] = 0;
}

// order-preserving float->uint transform (handles negatives exactly)
__device__ __forceinline__ unsigned fkey(float f) {
    unsigned u = __float_as_uint(f);
    return ((int)u >= 0) ? (u ^ 0x80000000u) : ~u;
}

// full bitonic sort of (hi,lo) u64 keys across 64 lanes, ascending.
// keys MUST be unique (ties break permutation property).
__device__ __forceinline__ void bitonic64(unsigned& hi, unsigned& lo, int lane) {
#pragma unroll
    for (int k = 2; k <= 64; k <<= 1) {
#pragma unroll
        for (int j = k >> 1; j > 0; j >>= 1) {
            unsigned ohi = __shfl_xor(hi, j, 64);
            unsigned olo = __shfl_xor(lo, j, 64);
            bool up    = ((lane & k) == 0);
            bool lower = ((lane & j) == 0);
            bool oless = (ohi < hi) || (ohi == hi && olo < lo);  // other < mine
            bool take  = (lower == up) ? oless : !oless;
            hi = take ? ohi : hi;
            lo = take ? olo : lo;
        }
    }
}

// slot (0..31) <-> tile-local candidate index mapping:
//   slot = tile*16 + it*4 + q   <->   jj = tile*1024 + it*256 + 4*lane + q
__device__ __forceinline__ unsigned slot_to_jj(int slot, int lane) {
    return (unsigned)(((slot >> 4) << 10) + (((slot >> 2) & 3) << 8) + (lane << 2) + (slot & 3));
}

// ---------------- kNN: one wave per row, LDS-staged candidates ----------------
__global__ __launch_bounds__(512) void knn_kernel(const float* __restrict__ x,
                                                  const float* __restrict__ xt,
                                                  const float* __restrict__ x2,
                                                  int* __restrict__ nbors,
                                                  int* __restrict__ indeg) {
    __shared__ __align__(16) float s_pl[11 * 1024];   // 44 KB candidate planes
    __shared__ unsigned s_hi[8][64];
    __shared__ unsigned s_lo[8][64];
    const int wv   = threadIdx.x >> 6;
    const int lane = threadIdx.x & 63;
    const int g  = blockIdx.x * 8 + wv;   // global row (node)
    const int bb = g >> 11;               // batch
    const int il = g & (NN_ - 1);         // local row index

    // own row (AoS, tiny)
    float xp[CDIM];
    const float* xr = x + (size_t)g * CDIM;
#pragma unroll
    for (int c = 0; c < CDIM; ++c) xp[c] = xr[c];

    const float* xtb = xt + (size_t)bb * CDIM * NN_;
    const float* x2b = x2 + bb * NN_;
    const float4* s_pl4 = (const float4*)s_pl;

    unsigned ud[32];
    unsigned min_hi = 0xFFFFFFFFu, min_lo = 0xFFFFFFFFu;

    for (int tile = 0; tile < 2; ++tile) {
        const int tb = tile << 10;
        __syncthreads();                 // previous tile fully consumed
        // stage 11 planes x 1024 candidates (coalesced: c constant per r)
        {
            const int t0 = threadIdx.x;
#pragma unroll
            for (int r = 0; r < 22; ++r) {
                const int idx = r * 512 + t0;
                const int c = idx >> 10;
                const int j = idx & 1023;
                s_pl[idx] = (c < 10) ? xtb[c * NN_ + tb + j] : x2b[tb + j];
            }
        }
        __syncthreads();
        // 4 groups of 256 candidates; lane handles 4 consecutive per group
#pragma unroll
        for (int it = 0; it < 4; ++it) {
            const int fo = it * 64 + lane;          // float4 offset within plane
            float4 dot = {0.f, 0.f, 0.f, 0.f};
#pragma unroll
            for (int c = 0; c < CDIM; ++c) {
                float4 v = s_pl4[c * 256 + fo];
                dot.x = fmaf(xp[c], v.x, dot.x);
                dot.y = fmaf(xp[c], v.y, dot.y);
                dot.z = fmaf(xp[c], v.z, dot.z);
                dot.w = fmaf(xp[c], v.w, dot.w);
            }
            const float4 xn = s_pl4[10 * 256 + fo];
            float kd[4];
            kd[0] = xn.x - 2.f * dot.x;
            kd[1] = xn.y - 2.f * dot.y;
            kd[2] = xn.z - 2.f * dot.z;
            kd[3] = xn.w - 2.f * dot.w;
            const int jbase = tb + it * 256 + (lane << 2);
#pragma unroll
            for (int q = 0; q < 4; ++q) {
                const int jj = jbase + q;
                unsigned u = fkey(kd[q]);
                if (jj == il) u = 0xFFFFFFFFu;      // exclude self
                ud[tile * 16 + it * 4 + q] = u;
                bool less = (u < min_hi) || (u == min_hi && (unsigned)jj < min_lo);
                min_hi = less ? u : min_hi;
                min_lo = less ? (unsigned)jj : min_lo;
            }
        }
    }

    // threshold M16 = 16th smallest lane-min
    unsigned bh = min_hi, bl = min_lo;
    bitonic64(bh, bl, lane);
    const unsigned m_hi = __shfl(bh, 15, 64);
    const unsigned m_lo = __shfl(bl, 15, 64);

    // count qualifying candidates per lane
    int c = 0;
#pragma unroll
    for (int slot = 0; slot < 32; ++slot) {
        const unsigned jj = slot_to_jj(slot, lane);
        const unsigned u  = ud[slot];
        bool q = (u < m_hi) || (u == m_hi && jj <= m_lo);
        c += q ? 1 : 0;
    }
    // exclusive prefix across lanes
    int pos = c;
#pragma unroll
    for (int m = 1; m < 64; m <<= 1) {
        int o = __shfl_up(pos, m, 64);
        if (lane >= m) pos += o;
    }
    const int total = __shfl(pos, 63, 64);
    pos -= c;

    if (total <= 64) {
        // compact to LDS (wave-private region; same-wave ds ordering via lgkmcnt)
#pragma unroll
        for (int slot = 0; slot < 32; ++slot) {
            const unsigned jj = slot_to_jj(slot, lane);
            const unsigned u  = ud[slot];
            bool q = (u < m_hi) || (u == m_hi && jj <= m_lo);
            if (q) { s_hi[wv][pos] = u; s_lo[wv][pos] = jj; pos++; }
        }
        unsigned u2 = (lane < total) ? s_hi[wv][lane] : 0xFFFFFFFFu;
        unsigned l2 = (lane < total) ? s_lo[wv][lane] : (0x80000000u + (unsigned)lane);
        bitonic64(u2, l2, lane);
        if (lane < KNN) {
            const int jglob = bb * NN_ + (int)l2;
            nbors[(size_t)g * KNN + lane] = jglob;
            atomicAdd(&indeg[jglob], 1);
        }
    } else {
        // exact fallback: 16 rounds of masked rescan + wave argmin (rare)
        unsigned taken = 0;
        for (int r = 0; r < KNN; ++r) {
            unsigned b_hi = 0xFFFFFFFFu, b_lo = 0xFFFFFFFFu;
#pragma unroll
            for (int slot = 0; slot < 32; ++slot) {
                const unsigned jj = slot_to_jj(slot, lane);
                const unsigned u  = ud[slot];
                bool avail = ((taken >> slot) & 1u) == 0u;
                bool less  = avail && ((u < b_hi) || (u == b_hi && jj < b_lo));
                b_hi = less ? u : b_hi;
                b_lo = less ? jj : b_lo;
            }
            unsigned w_hi = b_hi, w_lo = b_lo;
#pragma unroll
            for (int m = 32; m >= 1; m >>= 1) {
                unsigned oh = __shfl_xor(w_hi, m, 64);
                unsigned ol = __shfl_xor(w_lo, m, 64);
                bool less = (oh < w_hi) || (oh == w_hi && ol < w_lo);
                w_hi = less ? oh : w_hi;
                w_lo = less ? ol : w_lo;
            }
            if (b_hi == w_hi && b_lo == w_lo) {   // unique winner lane
                const int ws = ((int)(b_lo >> 10) << 4) + (((int)(b_lo >> 8) & 3) << 2) + (int)(b_lo & 3);
                taken |= 1u << ws;
                const int jglob = bb * NN_ + (int)w_lo;
                nbors[(size_t)g * KNN + r] = jglob;
                atomicAdd(&indeg[jglob], 1);
            }
        }
    }
}

// ---------------- exclusive scan over indeg (single block) ----------------
__global__ __launch_bounds__(1024) void scan_kernel(const int* __restrict__ indeg,
                                                    int* __restrict__ offs,
                                                    int* __restrict__ cursor) {
    __shared__ int part[1024];
    int t = threadIdx.x;
    int4 lv[8];
    int s = 0;
#pragma unroll
    for (int i = 0; i < 8; ++i) {
        lv[i] = ((const int4*)indeg)[t * 8 + i];
        s += lv[i].x + lv[i].y + lv[i].z + lv[i].w;
    }
    part[t] = s;
    __syncthreads();
    for (int d = 1; d < 1024; d <<= 1) {
        int add = (t >= d) ? part[t - d] : 0;
        __syncthreads();
        part[t] += add;
        __syncthreads();
    }
    int run = part[t] - s;
#pragma unroll
    for (int i = 0; i < 8; ++i) {
        int4 o;
        o.x = run; run += lv[i].x;
        o.y = run; run += lv[i].y;
        o.z = run; run += lv[i].z;
        o.w = run; run += lv[i].w;
        ((int4*)offs)[t * 8 + i]   = o;
        ((int4*)cursor)[t * 8 + i] = o;
    }
    if (t == 1023) offs[NNODES] = run;
}

// ---------------- fill reverse adjacency ----------------
__global__ __launch_bounds__(256) void fill_kernel(const int* __restrict__ nbors,
                                                   int* __restrict__ cursor,
                                                   int* __restrict__ rev) {
    int e = blockIdx.x * 256 + threadIdx.x;
    if (e >= NEDGES) return;
    int dst = nbors[e];
    int src = e >> 4;                 // KNN == 16
    int pos = atomicAdd(&cursor[dst], 1);
    rev[pos] = src;
}

// ---------------- layer 1 (CIN=10): old per-channel path ----------------
template<int CIN, int COUT, int GS, bool RELU>
__global__ __launch_bounds__(256) void layer_kernel(const float* __restrict__ in,
                                                    const float* __restrict__ wrel,
                                                    const float* __restrict__ wroot,
                                                    const float* __restrict__ bias,
                                                    const int* __restrict__ offs,
                                                    const int* __restrict__ rev,
                                                    float* __restrict__ out) {
    constexpr int NT = 8;                 // nodes per block
    __shared__ float s_ai[NT][CIN][2];    // [0]=agg, [1]=own row
    const int j0 = blockIdx.x * NT;
    const int t  = threadIdx.x;

    constexpr int NG = 256 / GS;
    const int grp = t / GS, cc = t % GS;
    for (int nt = grp; nt < NT; nt += NG) {
        const int j = j0 + nt;
        if (cc < CIN) s_ai[nt][cc][1] = in[(size_t)j * CIN + cc];
        float agg = 0.f;
        const int e0 = offs[j], e1 = offs[j + 1];
        for (int e = e0; e < e1; ++e) {
            const int s = rev[e];
            if (cc < CIN) agg += in[(size_t)s * CIN + cc];
        }
        if (cc < CIN) s_ai[nt][cc][0] = agg;
    }
    __syncthreads();

    constexpr int REP = 256 / COUT;
    constexpr int NPT = NT / REP;
    const int c = t % COUT, r = t / COUT;
    float acc[NPT];
#pragma unroll
    for (int u = 0; u < NPT; ++u) acc[u] = bias[c];
#pragma unroll 4
    for (int k = 0; k < CIN; ++k) {
        const float wrv = wrel[k * COUT + c];
        const float wov = wroot[k * COUT + c];
#pragma unroll
        for (int u = 0; u < NPT; ++u) {
            const int nt = r + u * REP;
            acc[u] = fmaf(s_ai[nt][k][0], wrv, acc[u]);
            acc[u] = fmaf(s_ai[nt][k][1], wov, acc[u]);
        }
    }
#pragma unroll
    for (int u = 0; u < NPT; ++u) {
        const int nt = r + u * REP;
        float v = acc[u];
        if (RELU) v = fmaxf(v, 0.f);
        out[(size_t)(j0 + nt) * COUT + c] = v;
    }
}

// ---------------- layers 2-4 (CIN=128): mini-GEMM layer ----------------
// NT=64 nodes/block (NPN=8 for COUT=128): halves the node-group weight
// replication traffic vs NT=32 (1 GB -> 512 MB from L2 per layer) at the
// same total LDS-read volume. acc[8][4]=32 VGPRs; LDS 64 KB -> 2 blocks/CU.
template<int COUT, bool RELU>
__global__ __launch_bounds__(256) void layer_big_kernel(const float* __restrict__ in,
                                                        const float* __restrict__ wrel,
                                                        const float* __restrict__ wroot,
                                                        const float* __restrict__ bias,
                                                        const int* __restrict__ offs,
                                                        const int* __restrict__ rev,
                                                        float* __restrict__ out) {
    constexpr int CIN = 128;
    constexpr int NT  = 64;               // nodes per block
    __shared__ float s_agg[NT][CIN];      // 32 KB
    __shared__ float s_own[NT][CIN];      // 32 KB
    const int j0 = blockIdx.x * NT;
    const int t  = threadIdx.x;

    // ---- stage: 8 node-groups in parallel, float4 per lane ----
    {
        const int ng  = t >> 5;           // 0..7
        const int c4  = (t & 31) * 4;     // channel group
#pragma unroll
        for (int r = 0; r < NT / 8; ++r) {
            const int nt = r * 8 + ng;
            const int j  = j0 + nt;
            float4 own = *(const float4*)(in + (size_t)j * CIN + c4);
            float4 a0 = {0.f,0.f,0.f,0.f}, a1 = a0, a2 = a0, a3 = a0;
            const int e0 = offs[j], e1 = offs[j + 1];
            int e = e0;
            for (; e + 4 <= e1; e += 4) {
                const int s0 = rev[e], s1 = rev[e+1], s2 = rev[e+2], s3 = rev[e+3];
                float4 v0 = *(const float4*)(in + (size_t)s0 * CIN + c4);
                float4 v1 = *(const float4*)(in + (size_t)s1 * CIN + c4);
                float4 v2 = *(const float4*)(in + (size_t)s2 * CIN + c4);
                float4 v3 = *(const float4*)(in + (size_t)s3 * CIN + c4);
                a0.x += v0.x; a0.y += v0.y; a0.z += v0.z; a0.w += v0.w;
                a1.x += v1.x; a1.y += v1.y; a1.z += v1.z; a1.w += v1.w;
                a2.x += v2.x; a2.y += v2.y; a2.z += v2.z; a2.w += v2.w;
                a3.x += v3.x; a3.y += v3.y; a3.z += v3.z; a3.w += v3.w;
            }
            for (; e < e1; ++e) {
                const int s0 = rev[e];
                float4 v0 = *(const float4*)(in + (size_t)s0 * CIN + c4);
                a0.x += v0.x; a0.y += v0.y; a0.z += v0.z; a0.w += v0.w;
            }
            float4 agg;
            agg.x = (a0.x + a1.x) + (a2.x + a3.x);
            agg.y = (a0.y + a1.y) + (a2.y + a3.y);
            agg.z = (a0.z + a1.z) + (a2.z + a3.z);
            agg.w = (a0.w + a1.w) + (a2.w + a3.w);
            *(float4*)(&s_agg[nt][c4]) = agg;
            *(float4*)(&s_own[nt][c4]) = own;
        }
    }
    __syncthreads();

    // ---- GEMM: out[n][c] = agg.wrel + own.wroot + bias ----
    constexpr int CG  = COUT / 4;         // col groups (32 or 16)
    constexpr int NGG = 256 / CG;         // node groups (8 or 16)
    constexpr int NPN = NT / NGG;         // nodes per thread (8 or 4)
    const int cg = t % CG, ng2 = t / CG;
    const int c4 = cg * 4;
    const int nb = ng2 * NPN;

    float acc[NPN][4];
    {
        const float4 b4 = *(const float4*)(bias + c4);
#pragma unroll
        for (int u = 0; u < NPN; ++u) {
            acc[u][0] = b4.x; acc[u][1] = b4.y; acc[u][2] = b4.z; acc[u][3] = b4.w;
        }
    }

#pragma unroll 2
    for (int k4 = 0; k4 < CIN; k4 += 4) {
        float4 wr_[4], wo_[4];
#pragma unroll
        for (int kk = 0; kk < 4; ++kk) {
            wr_[kk] = *(const float4*)(wrel  + (size_t)(k4 + kk) * COUT + c4);
            wo_[kk] = *(const float4*)(wroot + (size_t)(k4 + kk) * COUT + c4);
        }
#pragma unroll
        for (int u = 0; u < NPN; ++u) {
            const int n = nb + u;
            float4 ag = *(const float4*)(&s_agg[n][k4]);
            float4 ow = *(const float4*)(&s_own[n][k4]);
            acc[u][0] = fmaf(ag.x, wr_[0].x, acc[u][0]); acc[u][0] = fmaf(ag.y, wr_[1].x, acc[u][0]);
            acc[u][0] = fmaf(ag.z, wr_[2].x, acc[u][0]); acc[u][0] = fmaf(ag.w, wr_[3].x, acc[u][0]);
            acc[u][0] = fmaf(ow.x, wo_[0].x, acc[u][0]); acc[u][0] = fmaf(ow.y, wo_[1].x, acc[u][0]);
            acc[u][0] = fmaf(ow.z, wo_[2].x, acc[u][0]); acc[u][0] = fmaf(ow.w, wo_[3].x, acc[u][0]);

            acc[u][1] = fmaf(ag.x, wr_[0].y, acc[u][1]); acc[u][1] = fmaf(ag.y, wr_[1].y, acc[u][1]);
            acc[u][1] = fmaf(ag.z, wr_[2].y, acc[u][1]); acc[u][1] = fmaf(ag.w, wr_[3].y, acc[u][1]);
            acc[u][1] = fmaf(ow.x, wo_[0].y, acc[u][1]); acc[u][1] = fmaf(ow.y, wo_[1].y, acc[u][1]);
            acc[u][1] = fmaf(ow.z, wo_[2].y, acc[u][1]); acc[u][1] = fmaf(ow.w, wo_[3].y, acc[u][1]);

            acc[u][2] = fmaf(ag.x, wr_[0].z, acc[u][2]); acc[u][2] = fmaf(ag.y, wr_[1].z, acc[u][2]);
            acc[u][2] = fmaf(ag.z, wr_[2].z, acc[u][2]); acc[u][2] = fmaf(ag.w, wr_[3].z, acc[u][2]);
            acc[u][2] = fmaf(ow.x, wo_[0].z, acc[u][2]); acc[u][2] = fmaf(ow.y, wo_[1].z, acc[u][2]);
            acc[u][2] = fmaf(ow.z, wo_[2].z, acc[u][2]); acc[u][2] = fmaf(ow.w, wo_[3].z, acc[u][2]);

            acc[u][3] = fmaf(ag.x, wr_[0].w, acc[u][3]); acc[u][3] = fmaf(ag.y, wr_[1].w, acc[u][3]);
            acc[u][3] = fmaf(ag.z, wr_[2].w, acc[u][3]); acc[u][3] = fmaf(ag.w, wr_[3].w, acc[u][3]);
            acc[u][3] = fmaf(ow.x, wo_[0].w, acc[u][3]); acc[u][3] = fmaf(ow.y, wo_[1].w, acc[u][3]);
            acc[u][3] = fmaf(ow.z, wo_[2].w, acc[u][3]); acc[u][3] = fmaf(ow.w, wo_[3].w, acc[u][3]);
        }
    }

#pragma unroll
    for (int u = 0; u < NPN; ++u) {
        const int j = j0 + nb + u;
        float4 v;
        v.x = acc[u][0]; v.y = acc[u][1]; v.z = acc[u][2]; v.w = acc[u][3];
        if (RELU) {
            v.x = fmaxf(v.x, 0.f); v.y = fmaxf(v.y, 0.f);
            v.z = fmaxf(v.z, 0.f); v.w = fmaxf(v.w, 0.f);
        }
        *(float4*)(out + (size_t)j * COUT + c4) = v;
    }
}

// ---------------- final bilinear: out[b,i,j] = dot64(h[b,i], h[b,j]) ----------------
// Symmetric: compute only block-pairs bi<=bj (136 of 256 per batch).
// Off-diagonal pairs write both the straight tile and the mirror tile; the
// mirror comes straight from registers (acc[0..3][v] / acc[4..7][v] are
// contiguous along i), so no extra LDS traffic. Compute+LDS nearly halve.
#define EIDX(j) ((j) + ((j) >> 5))
__global__ __launch_bounds__(256) void edge_kernel(const float* __restrict__ h,
                                                   float* __restrict__ out) {
    __shared__ float tI[32][132];   // [k][EIDX(i)]
    __shared__ float tJ[32][132];   // [k][EIDX(j)]
    const int b = blockIdx.y;
    // pair index -> (bi, bj) with bi <= bj  (16 blocks per dim, 136 pairs)
    int rem = blockIdx.x;
    int bi = 0;
    while (rem >= 16 - bi) { rem -= 16 - bi; ++bi; }
    const int bj = bi + rem;
    const int i0 = bi * 128;
    const int j0 = bj * 128;
    const float* hb = h + (size_t)b * NN_ * 64;
    const int t = threadIdx.x;

    float acc[8][8];
#pragma unroll
    for (int u = 0; u < 8; ++u)
#pragma unroll
        for (int v = 0; v < 8; ++v) acc[u][v] = 0.f;

    const int ti = (t >> 4) * 8;      // 0..120
    const int tj = (t & 15) * 8;      // 0..120
    const int sr = t >> 1;            // staging row 0..127
    const int sg = (t & 1) * 16;      // staging k-segment

    for (int kc = 0; kc < 2; ++kc) {
        if (kc) __syncthreads();
        // stage 128 rows x 32 k each, transposed to k-major
        {
            const float* srcI = hb + (size_t)(i0 + sr) * 64 + kc * 32 + sg;
            const float* srcJ = hb + (size_t)(j0 + sr) * 64 + kc * 32 + sg;
            const int ri = EIDX(sr);
#pragma unroll
            for (int v = 0; v < 4; ++v) {
                float4 fi = *(const float4*)(srcI + v * 4);
                float4 fj = *(const float4*)(srcJ + v * 4);
                const int c = sg + v * 4;
                tI[c + 0][ri] = fi.x; tI[c + 1][ri] = fi.y;
                tI[c + 2][ri] = fi.z; tI[c + 3][ri] = fi.w;
                tJ[c + 0][ri] = fj.x; tJ[c + 1][ri] = fj.y;
                tJ[c + 2][ri] = fj.z; tJ[c + 3][ri] = fj.w;
            }
        }
        __syncthreads();

        const int ia = EIDX(ti), ja = EIDX(tj);
#pragma unroll 4
        for (int k = 0; k < 32; ++k) {
            float4 a0 = *(const float4*)(&tI[k][ia]);
            float4 a1 = *(const float4*)(&tI[k][ia + 4]);
            float4 b0 = *(const float4*)(&tJ[k][ja]);
            float4 b1 = *(const float4*)(&tJ[k][ja + 4]);
            float av[8] = {a0.x, a0.y, a0.z, a0.w, a1.x, a1.y, a1.z, a1.w};
            float bv[8] = {b0.x, b0.y, b0.z, b0.w, b1.x, b1.y, b1.z, b1.w};
#pragma unroll
            for (int u = 0; u < 8; ++u)
#pragma unroll
                for (int v = 0; v < 8; ++v) acc[u][v] = fmaf(av[u], bv[v], acc[u][v]);
        }
    }

    // straight tile (bi, bj)
#pragma unroll
    for (int u = 0; u < 8; ++u) {
        float* dst = out + ((size_t)b * NN_ + (i0 + ti + u)) * NN_ + (j0 + tj);
        float4 w0; w0.x = acc[u][0]; w0.y = acc[u][1]; w0.z = acc[u][2]; w0.w = acc[u][3];
        float4 w1; w1.x = acc[u][4]; w1.y = acc[u][5]; w1.z = acc[u][6]; w1.w = acc[u][7];
        *(float4*)(dst)     = w0;
        *(float4*)(dst + 4) = w1;
    }

    // mirror tile (bj, bi): out[b][j0+tj+v][i0+ti+u] = acc[u][v] (dot symmetric)
    if (bi != bj) {
#pragma unroll
        for (int v = 0; v < 8; ++v) {
            float* dstm = out + ((size_t)b * NN_ + (j0 + tj + v)) * NN_ + (i0 + ti);
            float4 m0; m0.x = acc[0][v]; m0.y = acc[1][v]; m0.z = acc[2][v]; m0.w = acc[3][v];
            float4 m1; m1.x = acc[4][v]; m1.y = acc[5][v]; m1.z = acc[6][v]; m1.w = acc[7][v];
            *(float4*)(dstm)     = m0;
            *(float4*)(dstm + 4) = m1;
        }
    }
}

extern "C" void kernel_launch(void* const* d_in, const int* in_sizes, int n_in,
                              void* d_out, int out_size, void* d_ws, size_t ws_size,
                              hipStream_t stream) {
    (void)in_sizes; (void)n_in; (void)out_size; (void)ws_size;
    const float* x = (const float*)d_in[0];
    const float* wr[4] = {(const float*)d_in[1],  (const float*)d_in[4],
                          (const float*)d_in[7],  (const float*)d_in[10]};
    const float* wo[4] = {(const float*)d_in[2],  (const float*)d_in[5],
                          (const float*)d_in[8],  (const float*)d_in[11]};
    const float* bs[4] = {(const float*)d_in[3],  (const float*)d_in[6],
                          (const float*)d_in[9],  (const float*)d_in[12]};
    float* out = (float*)d_out;

    char* w = (char*)d_ws;
    size_t o = 0;
    auto alloc = [&](size_t bytes) { void* p = w + o; o = (o + bytes + 255) & ~(size_t)255; return p; };
    int*   nbors  = (int*)  alloc((size_t)NEDGES * 4);
    int*   indeg  = (int*)  alloc((size_t)NNODES * 4);
    int*   offs   = (int*)  alloc((size_t)(NNODES + 1) * 4);
    int*   cursor = (int*)  alloc((size_t)NNODES * 4);
    int*   rev    = (int*)  alloc((size_t)NEDGES * 4);
    float* x2     = (float*)alloc((size_t)NNODES * 4);
    float* xt     = (float*)alloc((size_t)NNODES * CDIM * 4);
    float* hA     = (float*)alloc((size_t)NNODES * 128 * 4);
    float* hB     = (float*)alloc((size_t)NNODES * 128 * 4);

    prep_kernel<<<NNODES / 256, 256, 0, stream>>>(x, x2, xt, indeg);
    knn_kernel<<<NNODES / 8, 512, 0, stream>>>(x, xt, x2, nbors, indeg);
    scan_kernel<<<1, 1024, 0, stream>>>(indeg, offs, cursor);
    fill_kernel<<<NEDGES / 256, 256, 0, stream>>>(nbors, cursor, rev);

    layer_kernel<CDIM, 128, 16, true ><<<NNODES / 8, 256, 0, stream>>>(x,  wr[0], wo[0], bs[0], offs, rev, hA);
    layer_big_kernel<128, true ><<<NNODES / 64, 256, 0, stream>>>(hA, wr[1], wo[1], bs[1], offs, rev, hB);
    layer_big_kernel<128, true ><<<NNODES / 64, 256, 0, stream>>>(hB, wr[2], wo[2], bs[2], offs, rev, hA);
    layer_big_kernel<64,  false><<<NNODES / 64, 256, 0, stream>>>(hA, wr[3], wo[3], bs[3], offs, rev, hB);

    edge_kernel<<<dim3(136, 16, 1), 256, 0, stream>>>(hB, out);
}